// Round 1
// baseline (518.419 us; speedup 1.0000x reference)
//
#include <hip/hip_runtime.h>
#include <stdint.h>
#include <math.h>

#define IN_DIM 128
#define H_HEADS 8
#define HD 16

// ---------------- projection GEMM: q,k,v,skip = x @ W_p + b_p ----------------
// grid (ceil(N/64), 8), block 256. Tile 64 rows x 64 cols, K=128 fully staged.
__global__ __launch_bounds__(256)
void proj_gemm_kernel(const float* __restrict__ x,
                      const float* __restrict__ Wq, const float* __restrict__ bq,
                      const float* __restrict__ Wk, const float* __restrict__ bk,
                      const float* __restrict__ Wv, const float* __restrict__ bv,
                      const float* __restrict__ Wsk, const float* __restrict__ bsk,
                      float* __restrict__ qkvs, int N)
{
    __shared__ float As[64][132];   // row-major x tile, padded (132) to avoid staging conflicts
    __shared__ float Bs[128][64];   // W tile [k][c']
    const int t  = threadIdx.x;
    const int r0 = blockIdx.x * 64;
    const int ct = blockIdx.y;          // 0..7
    const int p  = ct >> 1;             // 0=q 1=k 2=v 3=skip
    const int cp0 = (ct & 1) * 64;      // column offset within the 128-wide projection
    const float* W    = (p == 0) ? Wq : (p == 1) ? Wk : (p == 2) ? Wv : Wsk;
    const float* bias = (p == 0) ? bq : (p == 1) ? bk : (p == 2) ? bv : bsk;
    float* outp = qkvs + (size_t)p * N * 128;

    // stage As = x[r0..r0+63][0..127]
#pragma unroll
    for (int j = 0; j < 8; ++j) {
        int f = t + j * 256;            // 2048 float4 loads total
        int m = f >> 5;                 // row in tile
        int k = (f & 31) << 2;          // col (k)
        float4 v = make_float4(0.f, 0.f, 0.f, 0.f);
        int gr = r0 + m;
        if (gr < N) v = *reinterpret_cast<const float4*>(x + (size_t)gr * 128 + k);
        *reinterpret_cast<float4*>(&As[m][k]) = v;
    }
    // stage Bs[k][c'] = W[h][k][d] with c = cp0+c', h=c/16, d=c%16
#pragma unroll
    for (int j = 0; j < 8; ++j) {
        int f = t + j * 256;
        int k = f >> 4;
        int c = (f & 15) << 2;
        int cc = cp0 + c;
        int h = cc >> 4, d = cc & 15;
        float4 v = *reinterpret_cast<const float4*>(W + ((size_t)h * IN_DIM + k) * HD + d);
        *reinterpret_cast<float4*>(&Bs[k][c]) = v;
    }
    __syncthreads();

    const int ty = t >> 4, tx = t & 15;
    float acc[4][4] = {};
    for (int k = 0; k < 128; k += 4) {
        float a[4][4], b[4][4];
#pragma unroll
        for (int i = 0; i < 4; ++i)
            *reinterpret_cast<float4*>(a[i]) = *reinterpret_cast<const float4*>(&As[ty * 4 + i][k]);
#pragma unroll
        for (int kk = 0; kk < 4; ++kk)
            *reinterpret_cast<float4*>(b[kk]) = *reinterpret_cast<const float4*>(&Bs[k + kk][tx * 4]);
#pragma unroll
        for (int i = 0; i < 4; ++i)
#pragma unroll
            for (int kk = 0; kk < 4; ++kk)
#pragma unroll
                for (int j = 0; j < 4; ++j)
                    acc[i][j] = fmaf(a[i][kk], b[kk][j], acc[i][j]);
    }

    const int cbase = cp0 + tx * 4;     // within-projection column 0..124
    float bv4[4];
#pragma unroll
    for (int j = 0; j < 4; ++j) bv4[j] = bias[cbase + j];
#pragma unroll
    for (int i = 0; i < 4; ++i) {
        int gr = r0 + ty * 4 + i;
        if (gr < N) {
            float4 o;
            o.x = acc[i][0] + bv4[0];
            o.y = acc[i][1] + bv4[1];
            o.z = acc[i][2] + bv4[2];
            o.w = acc[i][3] + bv4[3];
            *reinterpret_cast<float4*>(outp + (size_t)gr * 128 + cbase) = o;
        }
    }
}

// ---------------- degree histogram ----------------
__global__ void count_kernel(const int* __restrict__ ei, int* __restrict__ deg, int E)
{
    int e = blockIdx.x * 256 + threadIdx.x;
    if (e < E) atomicAdd(&deg[ei[E + e]], 1);   // dst row
}

// ---------------- exclusive scan (single block, shfl-based) ----------------
__global__ __launch_bounds__(1024)
void scan_kernel(const int* __restrict__ deg, int* __restrict__ offs,
                 int* __restrict__ cursor, int N)
{
    __shared__ int wsum[16];
    __shared__ int chunk_total_s;
    const int t = threadIdx.x;
    const int lane = t & 63, wid = t >> 6;
    int running = 0;
    for (int base = 0; base < N; base += 4096) {
        int v[4];
        int idx = base + t * 4;
#pragma unroll
        for (int j = 0; j < 4; ++j) { int i = idx + j; v[j] = (i < N) ? deg[i] : 0; }
        int ls = v[0] + v[1] + v[2] + v[3];
        int inc = ls;
#pragma unroll
        for (int off = 1; off < 64; off <<= 1) {
            int y = __shfl_up(inc, off);
            if (lane >= off) inc += y;
        }
        if (lane == 63) wsum[wid] = inc;
        __syncthreads();
        if (t < 16) {
            int winc = wsum[t];
            for (int off = 1; off < 16; off <<= 1) {
                int y = __shfl_up(winc, off);
                if (t >= off) winc += y;
            }
            wsum[t] = winc;
            if (t == 15) chunk_total_s = winc;
        }
        __syncthreads();
        int wexcl = (wid == 0) ? 0 : wsum[wid - 1];
        int texcl = running + wexcl + (inc - ls);
        int pre = 0;
#pragma unroll
        for (int j = 0; j < 4; ++j) {
            int i = idx + j;
            if (i < N) { offs[i] = texcl + pre; cursor[i] = texcl + pre; }
            pre += v[j];
        }
        running += chunk_total_s;
        __syncthreads();
    }
    if (t == 0) offs[N] = running;
}

// ---------------- scatter edges into CSR ----------------
__global__ void scatter_kernel(const int* __restrict__ ei, const float* __restrict__ ea,
                               int* __restrict__ cursor, int* __restrict__ csr_src,
                               float* __restrict__ csr_ea, int E)
{
    int e = blockIdx.x * 256 + threadIdx.x;
    if (e < E) {
        int s = ei[e], d = ei[E + e];
        int pos = atomicAdd(&cursor[d], 1);
        csr_src[pos] = s;
        csr_ea[pos]  = ea[e];
    }
}

// ---------------- per-node online-softmax attention + aggregation ----------------
// one wave per node: 64 lanes = 8 heads x 8 lanes, 2 dims per lane (col = 2*lane)
__global__ __launch_bounds__(256)
void agg_kernel(const float* __restrict__ qkvs, const int* __restrict__ offs,
                const int* __restrict__ csr_src, const float* __restrict__ csr_ea,
                const float* __restrict__ We, float* __restrict__ heads_cat, int N)
{
    const int lane = threadIdx.x & 63;
    const int node = blockIdx.x * 4 + (threadIdx.x >> 6);
    if (node >= N) return;
    const float* qb = qkvs;
    const float* kb = qkvs + (size_t)N * 128;
    const float* vb = qkvs + (size_t)2 * N * 128;
    const float* sb = qkvs + (size_t)3 * N * 128;

    const float2 q2  = *reinterpret_cast<const float2*>(qb + (size_t)node * 128 + 2 * lane);
    const float2 we2 = *reinterpret_cast<const float2*>(We + 2 * lane);

    float m = -__builtin_huge_valf();
    float ssum = 0.f, a0 = 0.f, a1 = 0.f;
    const int e0 = offs[node], e1 = offs[node + 1];
    for (int i = e0; i < e1; ++i) {
        const int   src = csr_src[i];
        const float eav = csr_ea[i];
        const float2 k2 = *reinterpret_cast<const float2*>(kb + (size_t)src * 128 + 2 * lane);
        const float2 v2 = *reinterpret_cast<const float2*>(vb + (size_t)src * 128 + 2 * lane);
        float ke0 = k2.x + eav * we2.x;
        float ke1 = k2.y + eav * we2.y;
        float dot = q2.x * ke0 + q2.y * ke1;
        dot += __shfl_xor(dot, 1);
        dot += __shfl_xor(dot, 2);
        dot += __shfl_xor(dot, 4);
        float alpha = dot * 0.25f;               // 1/sqrt(16)
        float nm = fmaxf(m, alpha);
        float sc = __expf(m - nm);               // m=-inf first iter -> 0
        float pv = __expf(alpha - nm);
        ssum = ssum * sc + pv;
        a0 = a0 * sc + pv * (v2.x + eav * we2.x);
        a1 = a1 * sc + pv * (v2.y + eav * we2.y);
        m = nm;
    }
    float inv = 1.0f / fmaxf(ssum, 1e-16f);
    const float2 sk = *reinterpret_cast<const float2*>(sb + (size_t)node * 128 + 2 * lane);
    float2 o;
    o.x = a0 * inv + sk.x;
    o.y = a1 * inv + sk.y;
    *reinterpret_cast<float2*>(heads_cat + (size_t)node * 128 + 2 * lane) = o;
}

// ---------------- output GEMM: pre = heads_cat @ Wo + bo + x ----------------
__global__ __launch_bounds__(256)
void out_gemm_kernel(const float* __restrict__ hc, const float* __restrict__ Wo,
                     const float* __restrict__ bo, const float* __restrict__ x,
                     float* __restrict__ pre, int N)
{
    __shared__ float As[64][132];
    __shared__ float Bs[128][64];
    const int t  = threadIdx.x;
    const int r0 = blockIdx.x * 64;
    const int c0 = blockIdx.y * 64;

#pragma unroll
    for (int j = 0; j < 8; ++j) {
        int f = t + j * 256;
        int m = f >> 5;
        int k = (f & 31) << 2;
        float4 v = make_float4(0.f, 0.f, 0.f, 0.f);
        int gr = r0 + m;
        if (gr < N) v = *reinterpret_cast<const float4*>(hc + (size_t)gr * 128 + k);
        *reinterpret_cast<float4*>(&As[m][k]) = v;
    }
#pragma unroll
    for (int j = 0; j < 8; ++j) {
        int f = t + j * 256;
        int k = f >> 4;
        int c = (f & 15) << 2;
        float4 v = *reinterpret_cast<const float4*>(Wo + (size_t)k * 128 + c0 + c);
        *reinterpret_cast<float4*>(&Bs[k][c]) = v;
    }
    __syncthreads();

    const int ty = t >> 4, tx = t & 15;
    float acc[4][4] = {};
    for (int k = 0; k < 128; k += 4) {
        float a[4][4], b[4][4];
#pragma unroll
        for (int i = 0; i < 4; ++i)
            *reinterpret_cast<float4*>(a[i]) = *reinterpret_cast<const float4*>(&As[ty * 4 + i][k]);
#pragma unroll
        for (int kk = 0; kk < 4; ++kk)
            *reinterpret_cast<float4*>(b[kk]) = *reinterpret_cast<const float4*>(&Bs[k + kk][tx * 4]);
#pragma unroll
        for (int i = 0; i < 4; ++i)
#pragma unroll
            for (int kk = 0; kk < 4; ++kk)
#pragma unroll
                for (int j = 0; j < 4; ++j)
                    acc[i][j] = fmaf(a[i][kk], b[kk][j], acc[i][j]);
    }

    const int cbase = c0 + tx * 4;
#pragma unroll
    for (int i = 0; i < 4; ++i) {
        int gr = r0 + ty * 4 + i;
        if (gr < N) {
            float4 xr = *reinterpret_cast<const float4*>(x + (size_t)gr * 128 + cbase);
            float4 o;
            o.x = acc[i][0] + bo[cbase + 0] + xr.x;
            o.y = acc[i][1] + bo[cbase + 1] + xr.y;
            o.z = acc[i][2] + bo[cbase + 2] + xr.z;
            o.w = acc[i][3] + bo[cbase + 3] + xr.w;
            *reinterpret_cast<float4*>(pre + (size_t)gr * 128 + cbase) = o;
        }
    }
}

// ---------------- LayerNorm: wave per node ----------------
__global__ __launch_bounds__(256)
void ln_kernel(const float* __restrict__ pre, const float* __restrict__ gamma,
               const float* __restrict__ beta, float* __restrict__ out, int N)
{
    const int lane = threadIdx.x & 63;
    const int node = blockIdx.x * 4 + (threadIdx.x >> 6);
    if (node >= N) return;
    float v0 = pre[(size_t)node * 128 + lane];
    float v1 = pre[(size_t)node * 128 + 64 + lane];
    float s = v0 + v1;
#pragma unroll
    for (int off = 1; off < 64; off <<= 1) s += __shfl_xor(s, off);
    float mean = s * (1.0f / 128.0f);
    float d0 = v0 - mean, d1 = v1 - mean;
    float sq = d0 * d0 + d1 * d1;
#pragma unroll
    for (int off = 1; off < 64; off <<= 1) sq += __shfl_xor(sq, off);
    float varv = sq * (1.0f / 128.0f);
    float inv = rsqrtf(varv + 1e-5f);
    out[(size_t)node * 128 + lane]      = d0 * inv * gamma[lane] + beta[lane];
    out[(size_t)node * 128 + 64 + lane] = d1 * inv * gamma[lane + 64] + beta[lane + 64];
}

extern "C" void kernel_launch(void* const* d_in, const int* in_sizes, int n_in,
                              void* d_out, int out_size, void* d_ws, size_t ws_size,
                              hipStream_t stream)
{
    const float* x    = (const float*)d_in[0];
    const int*   ei   = (const int*)d_in[1];
    const float* ea   = (const float*)d_in[2];
    const float* Wq   = (const float*)d_in[3];
    const float* bq   = (const float*)d_in[4];
    const float* Wk   = (const float*)d_in[5];
    const float* bk   = (const float*)d_in[6];
    const float* Wv   = (const float*)d_in[7];
    const float* bv   = (const float*)d_in[8];
    const float* We   = (const float*)d_in[9];
    const float* Wsk  = (const float*)d_in[10];
    const float* bsk  = (const float*)d_in[11];
    const float* Wo   = (const float*)d_in[12];
    const float* bo   = (const float*)d_in[13];
    const float* gamma= (const float*)d_in[14];
    const float* beta = (const float*)d_in[15];
    const int N = in_sizes[0] / 128;
    const int E = in_sizes[1] / 2;
    float* out = (float*)d_out;

    char* w = (char*)d_ws;
    float* qkvs      = (float*)w; w += (size_t)4 * N * 128 * sizeof(float);
    float* heads_cat = (float*)w; w += (size_t)N * 128 * sizeof(float);
    float* pre       = (float*)w; w += (size_t)N * 128 * sizeof(float);
    int*   deg       = (int*)w;   w += ((size_t)N + 16) * sizeof(int);
    int*   offs      = (int*)w;   w += ((size_t)N + 16) * sizeof(int);
    int*   cursor    = (int*)w;   w += ((size_t)N + 16) * sizeof(int);
    int*   csr_src   = (int*)w;   w += (size_t)E * sizeof(int);
    float* csr_ea    = (float*)w; w += (size_t)E * sizeof(float);

    hipMemsetAsync(deg, 0, (size_t)N * sizeof(int), stream);

    dim3 gProj((N + 63) / 64, 8);
    proj_gemm_kernel<<<gProj, 256, 0, stream>>>(x, Wq, bq, Wk, bk, Wv, bv, Wsk, bsk, qkvs, N);
    count_kernel<<<(E + 255) / 256, 256, 0, stream>>>(ei, deg, E);
    scan_kernel<<<1, 1024, 0, stream>>>(deg, offs, cursor, N);
    scatter_kernel<<<(E + 255) / 256, 256, 0, stream>>>(ei, ea, cursor, csr_src, csr_ea, E);
    agg_kernel<<<(N + 3) / 4, 256, 0, stream>>>(qkvs, offs, csr_src, csr_ea, We, heads_cat, N);
    dim3 gOut((N + 63) / 64, 2);
    out_gemm_kernel<<<gOut, 256, 0, stream>>>(heads_cat, Wo, bo, x, pre, N);
    ln_kernel<<<(N + 3) / 4, 256, 0, stream>>>(pre, gamma, beta, out, N);
}